// Round 1
// baseline (394.258 us; speedup 1.0000x reference)
//
#include <hip/hip_runtime.h>
#include <hip/hip_bf16.h>

#define NIN   128
#define NOUT  64
#define RANK  10
#define WLEN  101
#define TLEN  50000
#define TILE  1024
#define NT    49          // ceil(50000/1024)
#define TPAD  (NT * TILE) // 50176

// ---------------------------------------------------------------------------
// Repack K (rank,2,101) -> Kp (rank,2,104) zero-padded, 16B-aligned rows.
__global__ void k_prep(const float* __restrict__ K, float* __restrict__ Kp) {
    int idx = blockIdx.x * 256 + threadIdx.x;
    if (idx >= RANK * 2 * 104) return;
    int row = idx / 104, j = idx % 104;
    Kp[idx] = (j < WLEN) ? K[row * WLEN + j] : 0.f;
}

// ---------------------------------------------------------------------------
// Stage X tile (+50 halo each side) into LDS, zero-padded outside [0,TLEN).
__device__ __forceinline__ void stage_x(const float* __restrict__ Xn,
                                        float* xs, int tstart) {
    for (int p = threadIdx.x; p < TILE + 100; p += 256) {
        int g = tstart - 50 + p;
        xs[p] = (g >= 0 && g < TLEN) ? Xn[g] : 0.f;
    }
}

// Core direct conv: thread computes re/im for 4 consecutive t, all 10 ranks.
// c[t] = sum_j X[t+50-j] * Kc[k][j]; xs[p] = X[tstart-50+p].
__device__ __forceinline__ void conv_body(const float* xs,
                                          const float4* __restrict__ Kp,
                                          int tid,
                                          float (&re)[RANK][4],
                                          float (&im)[RANK][4]) {
#pragma unroll
    for (int k = 0; k < RANK; ++k)
#pragma unroll
        for (int i = 0; i < 4; ++i) { re[k][i] = 0.f; im[k][i] = 0.f; }

    const float4* xs4 = (const float4*)xs;
    for (int j4 = 0; j4 < 25; ++j4) {
        // window floats xs[tid*4 + 96-4*j4 .. +8): two aligned float4 reads
        float4 xa = xs4[tid + 24 - j4];
        float4 xb = xs4[tid + 25 - j4];
        float w[8] = {xa.x, xa.y, xa.z, xa.w, xb.x, xb.y, xb.z, xb.w};
#pragma unroll
        for (int k = 0; k < RANK; ++k) {
            float4 kr4 = Kp[(k * 2 + 0) * 26 + j4];
            float4 ki4 = Kp[(k * 2 + 1) * 26 + j4];
            const float* kr = (const float*)&kr4;
            const float* ki = (const float*)&ki4;
#pragma unroll
            for (int jo = 0; jo < 4; ++jo) {
#pragma unroll
                for (int i = 0; i < 4; ++i) {
                    re[k][i] = fmaf(w[4 - jo + i], kr[jo], re[k][i]);
                    im[k][i] = fmaf(w[4 - jo + i], ki[jo], im[k][i]);
                }
            }
        }
    }
    // epilogue: j = 100  (offsets 0..3 of window at j4=24 start)
    float4 xa = xs4[tid];
    const float* w4 = (const float*)&xa;
#pragma unroll
    for (int k = 0; k < RANK; ++k) {
        float kr = Kp[(k * 2 + 0) * 26 + 25].x;
        float ki = Kp[(k * 2 + 1) * 26 + 25].x;
#pragma unroll
        for (int i = 0; i < 4; ++i) {
            re[k][i] = fmaf(w4[i], kr, re[k][i]);
            im[k][i] = fmaf(w4[i], ki, im[k][i]);
        }
    }
}

// ---------------------------------------------------------------------------
// Pass 1: conv + |.|, optional store of c, per-(n,k) sum / sumsq via atomics.
template <int STORE_C>
__global__ void k_conv(const float* __restrict__ X,
                       const float4* __restrict__ Kp,
                       float* __restrict__ c,
                       float* __restrict__ sums,
                       float* __restrict__ sumsq) {
    __shared__ __align__(16) float xs[TILE + 104];
    __shared__ float red[4][2 * RANK];
    int n = blockIdx.y, tile = blockIdx.x, tid = threadIdx.x;
    int tstart = tile * TILE;
    stage_x(X + (size_t)n * TLEN, xs, tstart);
    __syncthreads();

    float re[RANK][4], im[RANK][4];
    conv_body(xs, Kp, tid, re, im);

    int tbase = tstart + tid * 4;
    float s1[RANK], s2[RANK];
#pragma unroll
    for (int k = 0; k < RANK; ++k) {
        float4 cv;
        float* cf = (float*)&cv;
        float a = 0.f, b = 0.f;
#pragma unroll
        for (int i = 0; i < 4; ++i) {
            float v = sqrtf(fmaf(re[k][i], re[k][i], im[k][i] * im[k][i]));
            cf[i] = v;
            float vm = (tbase + i < TLEN) ? v : 0.f;  // keep stats exact
            a += vm;
            b = fmaf(vm, vm, b);
        }
        s1[k] = a; s2[k] = b;
        if (STORE_C) {
            *(float4*)&c[((size_t)(n * RANK + k)) * TPAD + tbase] = cv;
        }
    }
    // wave64 shuffle reduce, then cross-wave via LDS, 20 atomics/block
#pragma unroll
    for (int k = 0; k < RANK; ++k) {
        for (int off = 32; off > 0; off >>= 1) {
            s1[k] += __shfl_down(s1[k], off);
            s2[k] += __shfl_down(s2[k], off);
        }
    }
    int wave = tid >> 6, lane = tid & 63;
    if (lane == 0) {
#pragma unroll
        for (int k = 0; k < RANK; ++k) {
            red[wave][k] = s1[k];
            red[wave][RANK + k] = s2[k];
        }
    }
    __syncthreads();
    if (tid < RANK) {
        float a = red[0][tid] + red[1][tid] + red[2][tid] + red[3][tid];
        atomicAdd(&sums[n * RANK + tid], a);
    } else if (tid >= 64 && tid < 64 + RANK) {
        int k = tid - 64;
        float b = red[0][RANK + k] + red[1][RANK + k] + red[2][RANK + k] + red[3][RANK + k];
        atomicAdd(&sumsq[n * RANK + k], b);
    }
}

// ---------------------------------------------------------------------------
// Finalize: W[n,k] = B1/std,  bias2[m] = bias[m] - sum mean*W*B2.
__global__ void k_fin(const float* __restrict__ sums,
                      const float* __restrict__ sumsq,
                      const float* __restrict__ B1,
                      const float* __restrict__ B2,
                      const float* __restrict__ bias,
                      float* __restrict__ Wm,
                      float* __restrict__ bias2) {
    __shared__ float mw[NIN * RANK];
    int tid = threadIdx.x;
    for (int idx = tid; idx < NIN * RANK; idx += 256) {
        float s = sums[idx], s2 = sumsq[idx];
        float mean = s / (float)TLEN;
        float var = fmaxf((s2 - s * mean) / (float)(TLEN - 1), 1e-12f);
        float w = B1[idx] / sqrtf(var);
        Wm[idx] = w;
        mw[idx] = mean * w;
    }
    __syncthreads();
    if (tid < NOUT) {
        float acc = bias[tid];
        for (int n = 0; n < NIN; ++n)
#pragma unroll
            for (int k = 0; k < RANK; ++k)
                acc -= mw[n * RANK + k] * B2[k * NOUT + tid];
        bias2[tid] = acc;
    }
}

// ---------------------------------------------------------------------------
// Pass 2 (BIG path): read c, y[k,t] partial over a 32-n chunk.
__global__ void k_comb(const float* __restrict__ c,
                       const float* __restrict__ Wm,
                       float* __restrict__ ypart) {
    int t2 = blockIdx.x * 256 + threadIdx.x;  // handles t = 2*t2, 2*t2+1
    int ch = blockIdx.y;
    float2 y[RANK];
#pragma unroll
    for (int k = 0; k < RANK; ++k) y[k] = make_float2(0.f, 0.f);
    int n0 = ch * (NIN / 4);
    for (int n = n0; n < n0 + NIN / 4; ++n) {
#pragma unroll
        for (int k = 0; k < RANK; ++k) {
            float2 cv = *(const float2*)&c[((size_t)(n * RANK + k)) * TPAD + 2 * t2];
            float w = Wm[n * RANK + k];
            y[k].x = fmaf(cv.x, w, y[k].x);
            y[k].y = fmaf(cv.y, w, y[k].y);
        }
    }
#pragma unroll
    for (int k = 0; k < RANK; ++k)
        *(float2*)&ypart[((size_t)(ch * RANK + k)) * TPAD + 2 * t2] = y[k];
}

// Pass 2 (SMALL path): recompute conv, accumulate y over an n-chunk.
__global__ void k_comb_re(const float* __restrict__ X,
                          const float4* __restrict__ Kp,
                          const float* __restrict__ Wm,
                          float* __restrict__ ypart, int npc) {
    __shared__ __align__(16) float xs[TILE + 104];
    int ch = blockIdx.y, tile = blockIdx.x, tid = threadIdx.x;
    int tstart = tile * TILE;
    float y[RANK][4];
#pragma unroll
    for (int k = 0; k < RANK; ++k)
#pragma unroll
        for (int i = 0; i < 4; ++i) y[k][i] = 0.f;

    int n0 = ch * npc;
    for (int n = n0; n < n0 + npc; ++n) {
        stage_x(X + (size_t)n * TLEN, xs, tstart);
        __syncthreads();
        float re[RANK][4], im[RANK][4];
        conv_body(xs, Kp, tid, re, im);
#pragma unroll
        for (int k = 0; k < RANK; ++k) {
            float w = Wm[n * RANK + k];
#pragma unroll
            for (int i = 0; i < 4; ++i) {
                float v = sqrtf(fmaf(re[k][i], re[k][i], im[k][i] * im[k][i]));
                y[k][i] = fmaf(v, w, y[k][i]);
            }
        }
        __syncthreads();  // xs reuse
    }
#pragma unroll
    for (int k = 0; k < RANK; ++k) {
        float4 v = make_float4(y[k][0], y[k][1], y[k][2], y[k][3]);
        *(float4*)&ypart[((size_t)(ch * RANK + k)) * TPAD + tstart + tid * 4] = v;
    }
}

// ---------------------------------------------------------------------------
// Final: out[m,t] = bias2[m] + sum_k B2[k,m] * sum_ch ypart[ch,k,t].
__global__ void k_out(const float* __restrict__ ypart,
                      const float* __restrict__ B2,
                      const float* __restrict__ bias2,
                      float* __restrict__ out, int nch) {
    int t2 = blockIdx.x * 256 + threadIdx.x;
    int t = 2 * t2;
    if (t >= TLEN) return;
    float2 y[RANK];
#pragma unroll
    for (int k = 0; k < RANK; ++k) y[k] = make_float2(0.f, 0.f);
    for (int ch = 0; ch < nch; ++ch) {
#pragma unroll
        for (int k = 0; k < RANK; ++k) {
            float2 v = *(const float2*)&ypart[((size_t)(ch * RANK + k)) * TPAD + t];
            y[k].x += v.x;
            y[k].y += v.y;
        }
    }
    for (int m = 0; m < NOUT; ++m) {
        float b = bias2[m];
        float2 acc = make_float2(b, b);
#pragma unroll
        for (int k = 0; k < RANK; ++k) {
            float w = B2[k * NOUT + m];
            acc.x = fmaf(y[k].x, w, acc.x);
            acc.y = fmaf(y[k].y, w, acc.y);
        }
        *(float2*)&out[(size_t)m * TLEN + t] = acc;
    }
}

// ---------------------------------------------------------------------------
extern "C" void kernel_launch(void* const* d_in, const int* in_sizes, int n_in,
                              void* d_out, int out_size, void* d_ws, size_t ws_size,
                              hipStream_t stream) {
    const float* X    = (const float*)d_in[0];
    const float* K    = (const float*)d_in[1];
    const float* B1   = (const float*)d_in[2];
    const float* B2   = (const float*)d_in[3];
    const float* bias = (const float*)d_in[4];
    float* out = (float*)d_out;

    char* p = (char*)d_ws;
    size_t off = 0;
    auto alloc = [&](size_t bytes) -> void* {
        void* r = p + off;
        off += (bytes + 255) & ~(size_t)255;
        return r;
    };
    float* sums  = (float*)alloc(NIN * RANK * sizeof(float));
    float* sumsq = (float*)alloc(NIN * RANK * sizeof(float));
    float* Wm    = (float*)alloc(NIN * RANK * sizeof(float));
    float* bias2 = (float*)alloc(NOUT * sizeof(float));
    float* Kp    = (float*)alloc(RANK * 2 * 104 * sizeof(float));

    size_t cbytes = (size_t)NIN * RANK * TPAD * sizeof(float);   // 256.9 MB
    size_t yp4    = (size_t)4 * RANK * TPAD * sizeof(float);
    size_t yp8    = (size_t)8 * RANK * TPAD * sizeof(float);

    int mode, nch;
    if (ws_size >= off + yp4 + 256 + cbytes)      { mode = 0; nch = 4; }
    else if (ws_size >= off + yp8)                { mode = 1; nch = 8; }
    else                                          { mode = 1; nch = 1; }

    float* ypart = (float*)alloc((size_t)nch * RANK * TPAD * sizeof(float));
    float* c     = (float*)(p + off);  // BIG path only

    // stats must start at zero (ws is poisoned 0xAA)
    hipMemsetAsync(sums, 0, 2 * NIN * RANK * sizeof(float), stream);

    k_prep<<<dim3((RANK * 2 * 104 + 255) / 256), 256, 0, stream>>>(K, Kp);

    if (mode == 0)
        k_conv<1><<<dim3(NT, NIN), 256, 0, stream>>>(X, (const float4*)Kp, c, sums, sumsq);
    else
        k_conv<0><<<dim3(NT, NIN), 256, 0, stream>>>(X, (const float4*)Kp, c, sums, sumsq);

    k_fin<<<1, 256, 0, stream>>>(sums, sumsq, B1, B2, bias, Wm, bias2);

    if (mode == 0) {
        k_comb<<<dim3(TPAD / 512, 4), 256, 0, stream>>>(c, Wm, ypart);
    } else {
        int npc = NIN / nch;
        k_comb_re<<<dim3(NT, nch), 256, 0, stream>>>(X, (const float4*)Kp, Wm, ypart, npc);
    }

    k_out<<<dim3(TPAD / 512), 256, 0, stream>>>(ypart, B2, bias2, out, nch);
}